// Round 15
// baseline (219.216 us; speedup 1.0000x reference)
//
#include <hip/hip_runtime.h>
#include <hip/hip_bf16.h>

#define B_ 16
#define C_ 256
#define H_ 128
#define W_ 128
#define K_ 12
#define HW_ (H_*W_)

typedef float vfloat4 __attribute__((ext_vector_type(4)));   // clang-native

__device__ __forceinline__ float gelu_exact(float v){
    return 0.5f * v * (1.0f + erff(v * 0.70710678118654752f));
}
// fast gelu: v * sigmoid(1.702 v); |err| <= 0.021 abs (threshold 0.199)
__device__ __forceinline__ float gelu_fast(float v){
    float e = __expf(-1.702f * v);
    return v * __builtin_amdgcn_rcpf(1.0f + e);
}
// pack two f32 -> bf16x2 (RNE) as plain unsigned (register-safe)
__device__ __forceinline__ unsigned pack2(float a, float b){
    __hip_bfloat162 h = __float22bfloat162_rn(make_float2(a, b));
    unsigned lo = (unsigned)__bfloat16_as_ushort(h.x);
    unsigned hi = (unsigned)__bfloat16_as_ushort(h.y);
    return (hi << 16) | lo;
}
__device__ __forceinline__ float bf16lo(unsigned u){ return __builtin_bit_cast(float, u << 16); }
__device__ __forceinline__ float bf16hi(unsigned u){ return __builtin_bit_cast(float, u & 0xFFFF0000u); }

// ---------------- Kernel 1: GAP over H,W per (b,c) plane ----------------
__global__ __launch_bounds__(256) void gap_kernel(const float* __restrict__ x,
                                                  float* __restrict__ y){
    int bc = blockIdx.x;                       // b*C + c
    const float4* p = (const float4*)(x + (size_t)bc * HW_);
    float s = 0.f;
    #pragma unroll
    for (int i = 0; i < 16; ++i){
        float4 v = p[i*256 + threadIdx.x];
        s += (v.x + v.y) + (v.z + v.w);
    }
    #pragma unroll
    for (int off = 32; off > 0; off >>= 1) s += __shfl_down(s, off, 64);
    __shared__ float red[4];
    int lane = threadIdx.x & 63, wv = threadIdx.x >> 6;
    if (lane == 0) red[wv] = s;
    __syncthreads();
    if (threadIdx.x == 0)
        y[bc] = (red[0]+red[1]+red[2]+red[3]) * (1.0f/(float)HW_);
}

// ------- Kernel 2: per-sample head; gate FOLDED into agg weights -------
__global__ __launch_bounds__(256) void head_kernel(
    const float* __restrict__ y, const float* __restrict__ w1,
    const float* __restrict__ b1, const float* __restrict__ w2,
    const float* __restrict__ b2, const float* __restrict__ kw,
    const float* __restrict__ eca,
    float* __restrict__ agg_out){

    __shared__ float y_s[C_];
    __shared__ float g_s[C_];
    __shared__ float p_s[C_];
    __shared__ float hdd_s[C_];
    __shared__ float logit_s[K_];
    __shared__ float alpha_s[K_];

    const int t = threadIdx.x;
    const int b = blockIdx.x;

    y_s[t] = y[b*C_ + t];
    __syncthreads();

    {   // ECA gate
        const float e0 = eca[0], e1 = eca[1], e2 = eca[2];
        float left  = (t > 0)      ? y_s[t-1] : 0.f;
        float right = (t < C_-1)   ? y_s[t+1] : 0.f;
        float arg = e0*left + e1*y_s[t] + e2*right;
        float g = 1.0f / (1.0f + expf(-arg));
        g_s[t] = g;
        p_s[t] = g * y_s[t];
    }
    __syncthreads();

    {   // MLP layer 1 (j = t)
        float acc = b1[t];
        #pragma unroll 8
        for (int i = 0; i < C_; ++i)
            acc = fmaf(p_s[i], w1[i*C_ + t], acc);
        hdd_s[t] = gelu_exact(acc);
    }
    __syncthreads();

    if (t < K_*16){   // layer-2 logits, 16 lanes per output
        const int k = t >> 4, s = t & 15;
        float acc = 0.f;
        #pragma unroll
        for (int i = 0; i < 16; ++i)
            acc = fmaf(hdd_s[s + i*16], w2[(s + i*16)*K_ + k], acc);
        #pragma unroll
        for (int off = 8; off > 0; off >>= 1) acc += __shfl_down(acc, off, 16);
        if (s == 0) logit_s[k] = acc + b2[k];
    }
    __syncthreads();

    if (t == 0){
        float m = -1e30f;
        #pragma unroll
        for (int k = 0; k < K_; ++k) m = fmaxf(m, logit_s[k]);
        float sum = 0.f, e[K_];
        #pragma unroll
        for (int k = 0; k < K_; ++k){ e[k] = expf(logit_s[k] - m); sum += e[k]; }
        float inv = 1.0f / sum;
        #pragma unroll
        for (int k = 0; k < K_; ++k) alpha_s[k] = e[k] * inv;
    }
    __syncthreads();

    // agg_w[c][ij] = gate[c] * sum_k alpha[k] * kw[k][c][ij]
    #pragma unroll
    for (int ii = 0; ii < 9; ++ii){
        int idx = t + ii*256;
        float acc = 0.f;
        #pragma unroll
        for (int k = 0; k < K_; ++k)
            acc = fmaf(alpha_s[k], kw[k*(C_*9) + idx], acc);
        agg_out[b*(C_*9) + idx] = acc * g_s[idx/9];
    }
}

// --------- Kernel 3: fused dwconv + LayerNorm(C) + GELU + residual ---------
// R14 anchor (shuffle w-neighbors, no xres stash, exact-f32 residual via
// L2/L3 re-read). Single change: channel-loop unroll 2 -> 4, batching 12
// float4 loads per wait group (2 wait points/thread instead of 4).
__global__ __launch_bounds__(256) void main_kernel(
    const float* __restrict__ x, const float* __restrict__ agg,
    const float* __restrict__ gamma, const float* __restrict__ beta,
    float* __restrict__ out)
{
    __shared__ float agg_s[C_*9];            // gate-folded, h-edge-zeroed
    __shared__ float gam_s[C_], bet_s[C_];
    __shared__ float psum[32*33];            // padded stride 33
    __shared__ float psumsq[32*33];
    __shared__ float mean_s[32], inv_s[32];

    const int t = threadIdx.x;

    // XCD-aware swizzle (bijective; 8192 % 8 == 0)
    const int wgid = blockIdx.x;             // 0..8191
    const int flat = (wgid & 7) * 1024 + (wgid >> 3);
    const int wt = flat & 3;                 // w-tile 0..3
    const int h  = (flat >> 2) & (H_-1);
    const int b  = flat >> 9;

    const bool r0ok = (h > 0), r2ok = (h < H_-1);
    for (int i = t; i < C_*9; i += 256){
        int r = (i % 9) / 3;
        float v = agg[b*(C_*9) + i];
        if ((r == 0 && !r0ok) || (r == 2 && !r2ok)) v = 0.f;
        agg_s[i] = v;
    }
    gam_s[t] = gamma[t]; bet_s[t] = beta[t];
    __syncthreads();

    const int s = t >> 3;            // channel slot 0..31
    const int q = t & 7;             // pixel quad 0..7
    const int w0 = wt*32 + q*4;

    const int ro0 = r0ok ? -W_ : 0;            // clamped row offsets
    const int ro2 = r2ok ?  W_ : 0;            // (zeroed coeffs kill them)
    const bool q0 = (q == 0), q7 = (q == 7);
    const bool eml = q0 && (w0 > 0);           // tile-boundary halo loads
    const bool epl = q7 && (w0 < W_-4);

    const float* xb = x + ((size_t)b * C_ + s) * HW_ + h * W_ + w0;

    unsigned conv_r[16];
    float s0=0,s1=0,s2=0,s3=0, q0s=0,q1s=0,q2s=0,q3s=0;

    #pragma unroll 4
    for (int kk = 0; kk < 8; ++kk){
        const int c = kk*32 + s;
        const float* xc = xb + (size_t)(kk*32) * HW_;
        const float4 vA = *(const float4*)(xc + ro0);
        const float4 vB = *(const float4*)(xc);
        const float4 vC = *(const float4*)(xc + ro2);
        float emA=0.f, emB=0.f, emC=0.f, epA=0.f, epB=0.f, epC=0.f;
        if (eml){ emA = (xc+ro0)[-1]; emB = xc[-1]; emC = (xc+ro2)[-1]; }
        if (epl){ epA = (xc+ro0)[4];  epB = xc[4];  epC = (xc+ro2)[4]; }

        const float k0 = agg_s[c*9+0], k1 = agg_s[c*9+1], k2 = agg_s[c*9+2];
        const float k3 = agg_s[c*9+3], k4 = agg_s[c*9+4], k5 = agg_s[c*9+5];
        const float k6 = agg_s[c*9+6], k7 = agg_s[c*9+7], k8 = agg_s[c*9+8];

        // w-neighbors from adjacent lane (same s, q+-1); q0/q7 lanes use the
        // halo scalar (zero at the true image edge).
        float vmA = __shfl_up(vA.w, 1, 64);   vmA = q0 ? emA : vmA;
        float vpA = __shfl_down(vA.x, 1, 64); vpA = q7 ? epA : vpA;
        float vmB = __shfl_up(vB.w, 1, 64);   vmB = q0 ? emB : vmB;
        float vpB = __shfl_down(vB.x, 1, 64); vpB = q7 ? epB : vpB;
        float vmC = __shfl_up(vC.w, 1, 64);   vmC = q0 ? emC : vmC;
        float vpC = __shfl_down(vC.x, 1, 64); vpC = q7 ? epC : vpC;

        float o0, o1, o2, o3;
        o0 = fmaf(vmA,  k0, fmaf(vA.x, k1, vA.y*k2));
        o1 = fmaf(vA.x, k0, fmaf(vA.y, k1, vA.z*k2));
        o2 = fmaf(vA.y, k0, fmaf(vA.z, k1, vA.w*k2));
        o3 = fmaf(vA.z, k0, fmaf(vA.w, k1, vpA *k2));

        o0 = fmaf(vmB,  k3, fmaf(vB.x, k4, fmaf(vB.y, k5, o0)));
        o1 = fmaf(vB.x, k3, fmaf(vB.y, k4, fmaf(vB.z, k5, o1)));
        o2 = fmaf(vB.y, k3, fmaf(vB.z, k4, fmaf(vB.w, k5, o2)));
        o3 = fmaf(vB.z, k3, fmaf(vB.w, k4, fmaf(vpB,  k5, o3)));

        o0 = fmaf(vmC,  k6, fmaf(vC.x, k7, fmaf(vC.y, k8, o0)));
        o1 = fmaf(vC.x, k6, fmaf(vC.y, k7, fmaf(vC.z, k8, o1)));
        o2 = fmaf(vC.y, k6, fmaf(vC.z, k7, fmaf(vC.w, k8, o2)));
        o3 = fmaf(vC.z, k6, fmaf(vC.w, k7, fmaf(vpC,  k8, o3)));

        conv_r[2*kk]   = pack2(o0, o1);
        conv_r[2*kk+1] = pack2(o2, o3);
        s0 += o0; s1 += o1; s2 += o2; s3 += o3;
        q0s = fmaf(o0,o0,q0s); q1s = fmaf(o1,o1,q1s);
        q2s = fmaf(o2,o2,q2s); q3s = fmaf(o3,o3,q3s);
    }

    *(float4*)&psum  [s*33 + q*4] = make_float4(s0,s1,s2,s3);
    *(float4*)&psumsq[s*33 + q*4] = make_float4(q0s,q1s,q2s,q3s);
    __syncthreads();

    if (t < 32){
        float sm = 0.f, qm = 0.f;
        #pragma unroll
        for (int g = 0; g < 32; ++g){ sm += psum[g*33 + t]; qm += psumsq[g*33 + t]; }
        float mean = sm * (1.0f/(float)C_);
        float var  = qm * (1.0f/(float)C_) - mean*mean;
        mean_s[t] = mean;
        inv_s[t]  = rsqrtf(var + 1e-6f);
    }
    __syncthreads();

    const float4 m4 = *(const float4*)&mean_s[q*4];
    const float4 i4 = *(const float4*)&inv_s[q*4];
    float* ob = out + ((size_t)b * C_ + s) * HW_ + h * W_ + w0;

    #pragma unroll
    for (int kk = 0; kk < 8; ++kk){
        const int c = kk*32 + s;
        const float gc = gam_s[c], bc = bet_s[c];
        const float4 xv = *(const float4*)(xb + (size_t)(kk*32) * HW_); // L2/L3-hot
        const float o0 = bf16lo(conv_r[2*kk]),   o1 = bf16hi(conv_r[2*kk]);
        const float o2 = bf16lo(conv_r[2*kk+1]), o3 = bf16hi(conv_r[2*kk+1]);
        const float y0 = fmaf((o0 - m4.x)*i4.x, gc, bc);
        const float y1 = fmaf((o1 - m4.y)*i4.y, gc, bc);
        const float y2 = fmaf((o2 - m4.z)*i4.z, gc, bc);
        const float y3 = fmaf((o3 - m4.w)*i4.w, gc, bc);
        vfloat4 r;
        r.x = gelu_fast(y0) + xv.x;
        r.y = gelu_fast(y1) + xv.y;
        r.z = gelu_fast(y2) + xv.z;
        r.w = gelu_fast(y3) + xv.w;
        __builtin_nontemporal_store(r, (vfloat4*)(ob + (size_t)(kk*32) * HW_));
    }
}

extern "C" void kernel_launch(void* const* d_in, const int* in_sizes, int n_in,
                              void* d_out, int out_size, void* d_ws, size_t ws_size,
                              hipStream_t stream){
    const float* x    = (const float*)d_in[0];
    const float* w1   = (const float*)d_in[1];
    const float* b1   = (const float*)d_in[2];
    const float* w2   = (const float*)d_in[3];
    const float* b2   = (const float*)d_in[4];
    const float* kw   = (const float*)d_in[5];
    const float* eca  = (const float*)d_in[6];
    const float* gam  = (const float*)d_in[7];
    const float* bet  = (const float*)d_in[8];
    float* out = (float*)d_out;

    float* y   = (float*)d_ws;           // B*C
    float* agg = y + B_*C_;              // B*C*9 (gate-folded)

    gap_kernel<<<B_*C_, 256, 0, stream>>>(x, y);
    head_kernel<<<B_, 256, 0, stream>>>(y, w1, b1, w2, b2, kw, eca, agg);
    main_kernel<<<B_*H_*4, 256, 0, stream>>>(x, agg, gam, bet, out);
}

// Round 16
// 186.333 us; speedup vs baseline: 1.1765x; 1.1765x over previous
//
#include <hip/hip_runtime.h>
#include <hip/hip_bf16.h>

#define B_ 16
#define C_ 256
#define H_ 128
#define W_ 128
#define K_ 12
#define HW_ (H_*W_)

typedef float vfloat4 __attribute__((ext_vector_type(4)));   // clang-native

__device__ __forceinline__ float gelu_exact(float v){
    return 0.5f * v * (1.0f + erff(v * 0.70710678118654752f));
}
// fast gelu: v * sigmoid(1.702 v); |err| <= 0.021 abs (threshold 0.199)
__device__ __forceinline__ float gelu_fast(float v){
    float e = __expf(-1.702f * v);
    return v * __builtin_amdgcn_rcpf(1.0f + e);
}
// pack two f32 -> bf16x2 (RNE) as plain unsigned (register-safe)
__device__ __forceinline__ unsigned pack2(float a, float b){
    __hip_bfloat162 h = __float22bfloat162_rn(make_float2(a, b));
    unsigned lo = (unsigned)__bfloat16_as_ushort(h.x);
    unsigned hi = (unsigned)__bfloat16_as_ushort(h.y);
    return (hi << 16) | lo;
}
__device__ __forceinline__ float bf16lo(unsigned u){ return __builtin_bit_cast(float, u << 16); }
__device__ __forceinline__ float bf16hi(unsigned u){ return __builtin_bit_cast(float, u & 0xFFFF0000u); }

// ---------------- Kernel 1: GAP over H,W per (b,c) plane ----------------
__global__ __launch_bounds__(256) void gap_kernel(const float* __restrict__ x,
                                                  float* __restrict__ y){
    int bc = blockIdx.x;                       // b*C + c
    const float4* p = (const float4*)(x + (size_t)bc * HW_);
    float s = 0.f;
    #pragma unroll
    for (int i = 0; i < 16; ++i){
        float4 v = p[i*256 + threadIdx.x];
        s += (v.x + v.y) + (v.z + v.w);
    }
    #pragma unroll
    for (int off = 32; off > 0; off >>= 1) s += __shfl_down(s, off, 64);
    __shared__ float red[4];
    int lane = threadIdx.x & 63, wv = threadIdx.x >> 6;
    if (lane == 0) red[wv] = s;
    __syncthreads();
    if (threadIdx.x == 0)
        y[bc] = (red[0]+red[1]+red[2]+red[3]) * (1.0f/(float)HW_);
}

// ------- Kernel 2: per-sample head; gate FOLDED into agg weights -------
__global__ __launch_bounds__(256) void head_kernel(
    const float* __restrict__ y, const float* __restrict__ w1,
    const float* __restrict__ b1, const float* __restrict__ w2,
    const float* __restrict__ b2, const float* __restrict__ kw,
    const float* __restrict__ eca,
    float* __restrict__ agg_out){

    __shared__ float y_s[C_];
    __shared__ float g_s[C_];
    __shared__ float p_s[C_];
    __shared__ float hdd_s[C_];
    __shared__ float logit_s[K_];
    __shared__ float alpha_s[K_];

    const int t = threadIdx.x;
    const int b = blockIdx.x;

    y_s[t] = y[b*C_ + t];
    __syncthreads();

    {   // ECA gate
        const float e0 = eca[0], e1 = eca[1], e2 = eca[2];
        float left  = (t > 0)      ? y_s[t-1] : 0.f;
        float right = (t < C_-1)   ? y_s[t+1] : 0.f;
        float arg = e0*left + e1*y_s[t] + e2*right;
        float g = 1.0f / (1.0f + expf(-arg));
        g_s[t] = g;
        p_s[t] = g * y_s[t];
    }
    __syncthreads();

    {   // MLP layer 1 (j = t)
        float acc = b1[t];
        #pragma unroll 8
        for (int i = 0; i < C_; ++i)
            acc = fmaf(p_s[i], w1[i*C_ + t], acc);
        hdd_s[t] = gelu_exact(acc);
    }
    __syncthreads();

    if (t < K_*16){   // layer-2 logits, 16 lanes per output
        const int k = t >> 4, s = t & 15;
        float acc = 0.f;
        #pragma unroll
        for (int i = 0; i < 16; ++i)
            acc = fmaf(hdd_s[s + i*16], w2[(s + i*16)*K_ + k], acc);
        #pragma unroll
        for (int off = 8; off > 0; off >>= 1) acc += __shfl_down(acc, off, 16);
        if (s == 0) logit_s[k] = acc + b2[k];
    }
    __syncthreads();

    if (t == 0){
        float m = -1e30f;
        #pragma unroll
        for (int k = 0; k < K_; ++k) m = fmaxf(m, logit_s[k]);
        float sum = 0.f, e[K_];
        #pragma unroll
        for (int k = 0; k < K_; ++k){ e[k] = expf(logit_s[k] - m); sum += e[k]; }
        float inv = 1.0f / sum;
        #pragma unroll
        for (int k = 0; k < K_; ++k) alpha_s[k] = e[k] * inv;
    }
    __syncthreads();

    // agg_w[c][ij] = gate[c] * sum_k alpha[k] * kw[k][c][ij]
    #pragma unroll
    for (int ii = 0; ii < 9; ++ii){
        int idx = t + ii*256;
        float acc = 0.f;
        #pragma unroll
        for (int k = 0; k < K_; ++k)
            acc = fmaf(alpha_s[k], kw[k*(C_*9) + idx], acc);
        agg_out[b*(C_*9) + idx] = acc * g_s[idx/9];
    }
}

// --------- Kernel 3: fused dwconv + LayerNorm(C) + GELU + residual ---------
// Best measured configuration (R14): shuffle w-neighbors, no xres stash
// (exact-f32 residual via L2/L3 re-read), channel-loop unroll 2.
// Unroll dose-response measured: 1 -> 209us, 2 -> ~188us, 4 -> 219us
// (VGPR 56 -> 56 -> 88; occupancy 41% -> ~42% -> 21%). 2 is the sweet spot.
__global__ __launch_bounds__(256) void main_kernel(
    const float* __restrict__ x, const float* __restrict__ agg,
    const float* __restrict__ gamma, const float* __restrict__ beta,
    float* __restrict__ out)
{
    __shared__ float agg_s[C_*9];            // gate-folded, h-edge-zeroed
    __shared__ float gam_s[C_], bet_s[C_];
    __shared__ float psum[32*33];            // padded stride 33
    __shared__ float psumsq[32*33];
    __shared__ float mean_s[32], inv_s[32];

    const int t = threadIdx.x;

    // XCD-aware swizzle (bijective; 8192 % 8 == 0)
    const int wgid = blockIdx.x;             // 0..8191
    const int flat = (wgid & 7) * 1024 + (wgid >> 3);
    const int wt = flat & 3;                 // w-tile 0..3
    const int h  = (flat >> 2) & (H_-1);
    const int b  = flat >> 9;

    const bool r0ok = (h > 0), r2ok = (h < H_-1);
    for (int i = t; i < C_*9; i += 256){
        int r = (i % 9) / 3;
        float v = agg[b*(C_*9) + i];
        if ((r == 0 && !r0ok) || (r == 2 && !r2ok)) v = 0.f;
        agg_s[i] = v;
    }
    gam_s[t] = gamma[t]; bet_s[t] = beta[t];
    __syncthreads();

    const int s = t >> 3;            // channel slot 0..31
    const int q = t & 7;             // pixel quad 0..7
    const int w0 = wt*32 + q*4;

    const int ro0 = r0ok ? -W_ : 0;            // clamped row offsets
    const int ro2 = r2ok ?  W_ : 0;            // (zeroed coeffs kill them)
    const bool q0 = (q == 0), q7 = (q == 7);
    const bool eml = q0 && (w0 > 0);           // tile-boundary halo loads
    const bool epl = q7 && (w0 < W_-4);

    const float* xb = x + ((size_t)b * C_ + s) * HW_ + h * W_ + w0;

    unsigned conv_r[16];
    float s0=0,s1=0,s2=0,s3=0, q0s=0,q1s=0,q2s=0,q3s=0;

    #pragma unroll 2
    for (int kk = 0; kk < 8; ++kk){
        const int c = kk*32 + s;
        const float* xc = xb + (size_t)(kk*32) * HW_;
        const float4 vA = *(const float4*)(xc + ro0);
        const float4 vB = *(const float4*)(xc);
        const float4 vC = *(const float4*)(xc + ro2);
        float emA=0.f, emB=0.f, emC=0.f, epA=0.f, epB=0.f, epC=0.f;
        if (eml){ emA = (xc+ro0)[-1]; emB = xc[-1]; emC = (xc+ro2)[-1]; }
        if (epl){ epA = (xc+ro0)[4];  epB = xc[4];  epC = (xc+ro2)[4]; }

        const float k0 = agg_s[c*9+0], k1 = agg_s[c*9+1], k2 = agg_s[c*9+2];
        const float k3 = agg_s[c*9+3], k4 = agg_s[c*9+4], k5 = agg_s[c*9+5];
        const float k6 = agg_s[c*9+6], k7 = agg_s[c*9+7], k8 = agg_s[c*9+8];

        // w-neighbors from adjacent lane (same s, q+-1); q0/q7 lanes use the
        // halo scalar (zero at the true image edge).
        float vmA = __shfl_up(vA.w, 1, 64);   vmA = q0 ? emA : vmA;
        float vpA = __shfl_down(vA.x, 1, 64); vpA = q7 ? epA : vpA;
        float vmB = __shfl_up(vB.w, 1, 64);   vmB = q0 ? emB : vmB;
        float vpB = __shfl_down(vB.x, 1, 64); vpB = q7 ? epB : vpB;
        float vmC = __shfl_up(vC.w, 1, 64);   vmC = q0 ? emC : vmC;
        float vpC = __shfl_down(vC.x, 1, 64); vpC = q7 ? epC : vpC;

        float o0, o1, o2, o3;
        o0 = fmaf(vmA,  k0, fmaf(vA.x, k1, vA.y*k2));
        o1 = fmaf(vA.x, k0, fmaf(vA.y, k1, vA.z*k2));
        o2 = fmaf(vA.y, k0, fmaf(vA.z, k1, vA.w*k2));
        o3 = fmaf(vA.z, k0, fmaf(vA.w, k1, vpA *k2));

        o0 = fmaf(vmB,  k3, fmaf(vB.x, k4, fmaf(vB.y, k5, o0)));
        o1 = fmaf(vB.x, k3, fmaf(vB.y, k4, fmaf(vB.z, k5, o1)));
        o2 = fmaf(vB.y, k3, fmaf(vB.z, k4, fmaf(vB.w, k5, o2)));
        o3 = fmaf(vB.z, k3, fmaf(vB.w, k4, fmaf(vpB,  k5, o3)));

        o0 = fmaf(vmC,  k6, fmaf(vC.x, k7, fmaf(vC.y, k8, o0)));
        o1 = fmaf(vC.x, k6, fmaf(vC.y, k7, fmaf(vC.z, k8, o1)));
        o2 = fmaf(vC.y, k6, fmaf(vC.z, k7, fmaf(vC.w, k8, o2)));
        o3 = fmaf(vC.z, k6, fmaf(vC.w, k7, fmaf(vpC,  k8, o3)));

        conv_r[2*kk]   = pack2(o0, o1);
        conv_r[2*kk+1] = pack2(o2, o3);
        s0 += o0; s1 += o1; s2 += o2; s3 += o3;
        q0s = fmaf(o0,o0,q0s); q1s = fmaf(o1,o1,q1s);
        q2s = fmaf(o2,o2,q2s); q3s = fmaf(o3,o3,q3s);
    }

    *(float4*)&psum  [s*33 + q*4] = make_float4(s0,s1,s2,s3);
    *(float4*)&psumsq[s*33 + q*4] = make_float4(q0s,q1s,q2s,q3s);
    __syncthreads();

    if (t < 32){
        float sm = 0.f, qm = 0.f;
        #pragma unroll
        for (int g = 0; g < 32; ++g){ sm += psum[g*33 + t]; qm += psumsq[g*33 + t]; }
        float mean = sm * (1.0f/(float)C_);
        float var  = qm * (1.0f/(float)C_) - mean*mean;
        mean_s[t] = mean;
        inv_s[t]  = rsqrtf(var + 1e-6f);
    }
    __syncthreads();

    const float4 m4 = *(const float4*)&mean_s[q*4];
    const float4 i4 = *(const float4*)&inv_s[q*4];
    float* ob = out + ((size_t)b * C_ + s) * HW_ + h * W_ + w0;

    #pragma unroll
    for (int kk = 0; kk < 8; ++kk){
        const int c = kk*32 + s;
        const float gc = gam_s[c], bc = bet_s[c];
        const float4 xv = *(const float4*)(xb + (size_t)(kk*32) * HW_); // L2/L3-hot
        const float o0 = bf16lo(conv_r[2*kk]),   o1 = bf16hi(conv_r[2*kk]);
        const float o2 = bf16lo(conv_r[2*kk+1]), o3 = bf16hi(conv_r[2*kk+1]);
        const float y0 = fmaf((o0 - m4.x)*i4.x, gc, bc);
        const float y1 = fmaf((o1 - m4.y)*i4.y, gc, bc);
        const float y2 = fmaf((o2 - m4.z)*i4.z, gc, bc);
        const float y3 = fmaf((o3 - m4.w)*i4.w, gc, bc);
        vfloat4 r;
        r.x = gelu_fast(y0) + xv.x;
        r.y = gelu_fast(y1) + xv.y;
        r.z = gelu_fast(y2) + xv.z;
        r.w = gelu_fast(y3) + xv.w;
        __builtin_nontemporal_store(r, (vfloat4*)(ob + (size_t)(kk*32) * HW_));
    }
}

extern "C" void kernel_launch(void* const* d_in, const int* in_sizes, int n_in,
                              void* d_out, int out_size, void* d_ws, size_t ws_size,
                              hipStream_t stream){
    const float* x    = (const float*)d_in[0];
    const float* w1   = (const float*)d_in[1];
    const float* b1   = (const float*)d_in[2];
    const float* w2   = (const float*)d_in[3];
    const float* b2   = (const float*)d_in[4];
    const float* kw   = (const float*)d_in[5];
    const float* eca  = (const float*)d_in[6];
    const float* gam  = (const float*)d_in[7];
    const float* bet  = (const float*)d_in[8];
    float* out = (float*)d_out;

    float* y   = (float*)d_ws;           // B*C
    float* agg = y + B_*C_;              // B*C*9 (gate-folded)

    gap_kernel<<<B_*C_, 256, 0, stream>>>(x, y);
    head_kernel<<<B_, 256, 0, stream>>>(y, w1, b1, w2, b2, kw, eca, agg);
    main_kernel<<<B_*H_*4, 256, 0, stream>>>(x, agg, gam, bet, out);
}